// Round 8
// baseline (280.676 us; speedup 1.0000x reference)
//
#include <hip/hip_runtime.h>
#include <stdint.h>

#define BATCH 32
#define CIN   64
#define HH    112
#define WW    112
#define COUT_ 64
#define ROWB  7296                      // 114 cols * 64 B per LDS row

typedef int v4i __attribute__((ext_vector_type(4)));

// Weight transpose: [co][ci][kh][kw] -> [co][tap][ci] so A-fragments
// (16 consecutive k = contiguous ci at a fixed tap) are direct loads.
__global__ void wtrans_kernel(const int* __restrict__ wq, int8_t* __restrict__ wt) {
    int idx = blockIdx.x * 256 + threadIdx.x;   // 0 .. 36863, exact
    int ci   = idx & 63;
    int khkw = (idx >> 6) % 9;
    int co   = idx / 576;
    wt[idx] = (int8_t)wq[co * 576 + ci * 9 + khkw];
}

// Fused conv v9: producer-consumer wave specialization, 2 blocks/CU.
// 512 blocks = 32 b x 16 h-groups of 7 output rows; 512 threads = 2 groups
// of 4 waves. 8-row LDS ring (58,368 B; x2 = 117 KB/CU, fits 160 KB).
// 4 phases: tiles of 2+2+2+1 rows. Group (ph&1) computes tile ph; the other
// group drains its 2-phase-old loads, ds_writes the next ring rows, stores
// its previously-computed tile, issues loads 2 phases ahead. Ring safety:
// every ring row is written >= 1 barrier after its last read (checked per
// phase below). Two co-resident blocks interleave to cover drains/barriers.
__launch_bounds__(512, 4)
__global__ void conv7_kernel(const int* __restrict__ x,
                             const int8_t* __restrict__ wt,
                             const float*  __restrict__ wscale,
                             const float*  __restrict__ ascale,
                             const float*  __restrict__ bias,
                             float*        __restrict__ out) {
    __shared__ int8_t xs[8 * ROWB];   // 58,368 B ring

    const int tid  = threadIdx.x;          // 0..511
    const int g    = tid >> 8;             // wave-group 0/1
    const int stid = tid & 255;            // id within group
    // XCD-chunked swizzle: 512 = 8 XCDs x 64 contiguous (b, hg) groups
    const int bt = ((blockIdx.x & 7) * 64) + (blockIdx.x >> 3);
    const int b  = bt >> 4;                // /16
    const int hb = (bt & 15) * 7;          // 7 output rows per block

    const int lane = tid & 63;
    const int wave = (tid >> 6) & 3;       // co-tile within group
    const int ln15 = lane & 15;
    const int quad = lane >> 4;

    // one-time: zero W-pad columns 0 and 113 of all 8 ring rows (256 jobs)
    if (tid < 256) {
        int pr   = tid >> 5;
        int side = (tid >> 4) & 1;
        int d    = tid & 15;
        *(uint32_t*)&xs[pr * ROWB + (side ? 113 : 0) * 64 + d * 4] = 0u;
    }

    // A fragments: wt[co][tap*64 + quad*16 .. +15]
    const v4i* wrow = (const v4i*)(wt + (size_t)(wave * 16 + ln15) * 576);
    v4i a[9];
    #pragma unroll
    for (int t = 0; t < 9; ++t) a[t] = wrow[t * 4 + quad];

    const float s = ascale[0] * wscale[0];
    float bv[4];
    #pragma unroll
    for (int reg = 0; reg < 4; ++reg) bv[reg] = bias[wave * 16 + quad * 4 + reg];

    // ---- group-local staging: load to regs / narrow+swizzle to LDS ----
    // 2-row: 896 jobs over 256 group-threads (4 int4 loads each, coalesced
    // 64B lines). 1-row: 448 jobs. OOB rows stay zero (H padding).
    v4i q[16];
    auto stage_load = [&](int hstart) {
        #pragma unroll
        for (int it = 0; it < 4; ++it) {
            #pragma unroll
            for (int p = 0; p < 4; ++p) q[it * 4 + p] = (v4i){0, 0, 0, 0};
            int job = stid + it * 256;
            if (job < 896) {
                int ci4  = job & 15;
                int cg   = (job >> 4) % 28;
                int row2 = job / 448;
                int hh   = hstart + row2;
                if (hh >= 0 && hh < HH) {
                    const v4i* gp = (const v4i*)
                        (x + ((size_t)(b * CIN + ci4 * 4) * HH + hh) * WW + cg * 4);
                    q[it * 4 + 0] = gp[0];
                    q[it * 4 + 1] = gp[3136];      // +1 ci plane
                    q[it * 4 + 2] = gp[2 * 3136];
                    q[it * 4 + 3] = gp[3 * 3136];
                }
            }
        }
    };
    auto stage_load1 = [&](int hh) {       // single row -> q[0..7]
        #pragma unroll
        for (int it = 0; it < 2; ++it) {
            #pragma unroll
            for (int p = 0; p < 4; ++p) q[it * 4 + p] = (v4i){0, 0, 0, 0};
            int job = stid + it * 256;
            if (job < 448 && hh >= 0 && hh < HH) {
                int ci4 = job & 15;
                int cg  = (job >> 4) % 28;
                const v4i* gp = (const v4i*)
                    (x + ((size_t)(b * CIN + ci4 * 4) * HH + hh) * WW + cg * 4);
                q[it * 4 + 0] = gp[0];
                q[it * 4 + 1] = gp[3136];
                q[it * 4 + 2] = gp[2 * 3136];
                q[it * 4 + 3] = gp[3 * 3136];
            }
        }
    };
    auto stage_write = [&](int pb) {       // 2 rows at ring pb, pb+1
        #pragma unroll
        for (int it = 0; it < 4; ++it) {
            int job = stid + it * 256;
            if (job < 896) {
                int ci4  = job & 15;
                int cg   = (job >> 4) % 28;
                int row2 = job / 448;
                int8_t* rowp = &xs[(pb + row2) * ROWB];
                #pragma unroll
                for (int j = 0; j < 4; ++j) {
                    uint32_t lo01 = __builtin_amdgcn_perm(
                        (uint32_t)q[it * 4 + 1][j], (uint32_t)q[it * 4 + 0][j], 0x0C0C0400u);
                    uint32_t lo23 = __builtin_amdgcn_perm(
                        (uint32_t)q[it * 4 + 3][j], (uint32_t)q[it * 4 + 2][j], 0x04000C0Cu);
                    int col = cg * 4 + 1 + j;   // +1: W-pad shift
                    int sd  = (((ci4 >> 2) ^ ((col >> 1) & 3)) << 2) | (ci4 & 3);
                    *(uint32_t*)&rowp[col * 64 + sd * 4] = lo01 | lo23;
                }
            }
        }
    };
    auto stage_write1 = [&](int pb) {      // 1 row at ring pb
        #pragma unroll
        for (int it = 0; it < 2; ++it) {
            int job = stid + it * 256;
            if (job < 448) {
                int ci4 = job & 15;
                int cg  = (job >> 4) % 28;
                int8_t* rowp = &xs[pb * ROWB];
                #pragma unroll
                for (int j = 0; j < 4; ++j) {
                    uint32_t lo01 = __builtin_amdgcn_perm(
                        (uint32_t)q[it * 4 + 1][j], (uint32_t)q[it * 4 + 0][j], 0x0C0C0400u);
                    uint32_t lo23 = __builtin_amdgcn_perm(
                        (uint32_t)q[it * 4 + 3][j], (uint32_t)q[it * 4 + 2][j], 0x04000C0Cu);
                    int col = cg * 4 + 1 + j;
                    int sd  = (((ci4 >> 2) ^ ((col >> 1) & 3)) << 2) | (ci4 & 3);
                    *(uint32_t*)&rowp[col * 64 + sd * 4] = lo01 | lo23;
                }
            }
        }
    };

    v4i acc[2][7];
    // 2-row tile at ring rows rbase..rbase+3 (never wraps for rbase 0/2/4);
    // each bfrag feeds acc[0] (kh=rho) and acc[1] (kh=rho-1):
    // 84 ds_read_b128 : 126 MFMA per wave, conflict-free swizzle.
    auto mfma_tile = [&](int rbase) {
        #pragma unroll
        for (int r = 0; r < 2; ++r)
            #pragma unroll
            for (int nt = 0; nt < 7; ++nt)
                acc[r][nt] = (v4i){0, 0, 0, 0};
        #pragma unroll
        for (int rho = 0; rho < 4; ++rho) {
            const int pr = rbase + rho;
            #pragma unroll
            for (int kw = 0; kw < 3; ++kw) {
                const int m   = ln15 + kw;
                const int swz = (quad ^ ((m >> 1) & 3)) << 4;
                const int8_t* bp = &xs[pr * ROWB + m * 64 + swz];
                #pragma unroll
                for (int nt = 0; nt < 7; ++nt) {
                    v4i bfrag = *(const v4i*)(bp + nt * 1024);
                    if (rho <= 2)
                        acc[0][nt] = __builtin_amdgcn_mfma_i32_16x16x64_i8(
                            a[rho * 3 + kw], bfrag, acc[0][nt], 0, 0, 0);
                    if (rho >= 1)
                        acc[1][nt] = __builtin_amdgcn_mfma_i32_16x16x64_i8(
                            a[(rho - 1) * 3 + kw], bfrag, acc[1][nt], 0, 0, 0);
                }
            }
        }
    };
    // single-row tile (out row hb+6): ring rows {6,7,0}, acc[0] only.
    auto mfma_last = [&]() {
        #pragma unroll
        for (int nt = 0; nt < 7; ++nt) acc[0][nt] = (v4i){0, 0, 0, 0};
        #pragma unroll
        for (int rho = 0; rho < 3; ++rho) {
            const int pr = (6 + rho) & 7;
            #pragma unroll
            for (int kw = 0; kw < 3; ++kw) {
                const int m   = ln15 + kw;
                const int swz = (quad ^ ((m >> 1) & 3)) << 4;
                const int8_t* bp = &xs[pr * ROWB + m * 64 + swz];
                #pragma unroll
                for (int nt = 0; nt < 7; ++nt) {
                    v4i bfrag = *(const v4i*)(bp + nt * 1024);
                    acc[0][nt] = __builtin_amdgcn_mfma_i32_16x16x64_i8(
                        a[rho * 3 + kw], bfrag, acc[0][nt], 0, 0, 0);
                }
            }
        }
    };
    auto store_tile = [&](int t) {         // 2 rows
        const int h0 = hb + 2 * t;
        #pragma unroll
        for (int r = 0; r < 2; ++r) {
            const int h = h0 + r;
            #pragma unroll
            for (int reg = 0; reg < 4; ++reg) {
                int co = wave * 16 + quad * 4 + reg;
                float* op = out + ((size_t)(b * COUT_ + co) * HH + h) * WW;
                #pragma unroll
                for (int nt = 0; nt < 7; ++nt)
                    op[nt * 16 + ln15] = (float)acc[r][nt][reg] * s + bv[reg];
            }
        }
    };
    auto store_last = [&]() {              // 1 row (hb+6), acc[0]
        const int h = hb + 6;
        #pragma unroll
        for (int reg = 0; reg < 4; ++reg) {
            int co = wave * 16 + quad * 4 + reg;
            float* op = out + ((size_t)(b * COUT_ + co) * HH + h) * WW;
            #pragma unroll
            for (int nt = 0; nt < 7; ++nt)
                op[nt * 16 + ln15] = (float)acc[0][nt][reg] * s + bv[reg];
        }
    };

    // ---- prologue ----
    // g0 stages ring 0,1 (in-rows hb-1,hb); g1 stages ring 2,3 (hb+1,hb+2)
    stage_load(hb - 1 + 2 * g);
    asm volatile("s_waitcnt vmcnt(0)" ::: "memory");
    stage_write(2 * g);
    // issue-ahead: g1 loads hb+3,hb+4 (writes ring 4,5 at ph0);
    //              g0 loads hb+5,hb+6 (writes ring 6,7 at ph1)
    stage_load(hb + 3 + 2 * (g ^ 1));
    asm volatile("s_waitcnt lgkmcnt(0)" ::: "memory");
    __builtin_amdgcn_s_barrier();
    __builtin_amdgcn_sched_barrier(0);

    // ---- ph0: g0 computes tile0 (rings 0-3); g1 writes rings 4,5 +
    //          issues the hb+7 load (ring 0 at ph2) ----
    if (g == 0) {
        __builtin_amdgcn_s_setprio(1);
        mfma_tile(0);
        __builtin_amdgcn_s_setprio(0);
    } else {
        asm volatile("s_waitcnt vmcnt(0)" ::: "memory");
        stage_write(4);
        stage_load1(hb + 7);
    }
    __builtin_amdgcn_sched_barrier(0);
    asm volatile("s_waitcnt lgkmcnt(0)" ::: "memory");
    __builtin_amdgcn_s_barrier();
    __builtin_amdgcn_sched_barrier(0);

    // ---- ph1: g1 computes tile1 (rings 2-5); g0 writes rings 6,7 and
    //          stores tile0 ----
    if (g == 1) {
        __builtin_amdgcn_s_setprio(1);
        mfma_tile(2);
        __builtin_amdgcn_s_setprio(0);
    } else {
        asm volatile("s_waitcnt vmcnt(0)" ::: "memory");
        stage_write(6);
        store_tile(0);
    }
    __builtin_amdgcn_sched_barrier(0);
    asm volatile("s_waitcnt lgkmcnt(0)" ::: "memory");
    __builtin_amdgcn_s_barrier();
    __builtin_amdgcn_sched_barrier(0);

    // ---- ph2: g0 computes tile2 (rings 4-7); g1 writes ring 0 (in-row
    //          hb+7; last read at ph0, barrier since) and stores tile1 ----
    if (g == 0) {
        __builtin_amdgcn_s_setprio(1);
        mfma_tile(4);
        __builtin_amdgcn_s_setprio(0);
    } else {
        asm volatile("s_waitcnt vmcnt(0)" ::: "memory");
        stage_write1(0);
        store_tile(1);
    }
    __builtin_amdgcn_sched_barrier(0);
    asm volatile("s_waitcnt lgkmcnt(0)" ::: "memory");
    __builtin_amdgcn_s_barrier();
    __builtin_amdgcn_sched_barrier(0);

    // ---- ph3: g1 computes the single-row tile3 (rings 6,7,0); g0 stores
    //          tile2; then g1 stores tile3 ----
    if (g == 1) {
        __builtin_amdgcn_s_setprio(1);
        mfma_last();
        __builtin_amdgcn_s_setprio(0);
        store_last();
    } else {
        store_tile(2);
    }
}

extern "C" void kernel_launch(void* const* d_in, const int* in_sizes, int n_in,
                              void* d_out, int out_size, void* d_ws, size_t ws_size,
                              hipStream_t stream) {
    const int*    xq     = (const int*)d_in[0];
    const int*    wq     = (const int*)d_in[1];
    const float*  wscale = (const float*)d_in[2];
    const float*  ascale = (const float*)d_in[3];
    const float*  bias   = (const float*)d_in[4];
    int8_t* wt  = (int8_t*)d_ws;          // 36,864 B scratch
    float*  out = (float*)d_out;

    wtrans_kernel<<<144, 256, 0, stream>>>(wq, wt);
    conv7_kernel<<<512, 512, 0, stream>>>(xq, wt, wscale, ascale, bias, out);
}

// Round 9
// 197.473 us; speedup vs baseline: 1.4213x; 1.4213x over previous
//
#include <hip/hip_runtime.h>
#include <stdint.h>

#define BATCH 32
#define CIN   64
#define HH    112
#define WW    112
#define COUT_ 64
#define ROWB  7296                      // 114 cols * 64 B per LDS row

typedef int v4i __attribute__((ext_vector_type(4)));

// Weight transpose: [co][ci][kh][kw] -> [co][tap][ci] so A-fragments
// (16 consecutive k = contiguous ci at a fixed tap) are direct loads.
__global__ void wtrans_kernel(const int* __restrict__ wq, int8_t* __restrict__ wt) {
    int idx = blockIdx.x * 256 + threadIdx.x;   // 0 .. 36863, exact
    int ci   = idx & 63;
    int khkw = (idx >> 6) % 9;
    int co   = idx / 576;
    wt[idx] = (int8_t)wq[co * 576 + ci * 9 + khkw];
}

// Fused conv v9b: producer-consumer wave specialization, 2 blocks/CU.
// 512 blocks = 32 b x 16 h-groups of 7 output rows; 512 threads = 2 groups
// of 4 waves. 8-row LDS ring (58,368 B; x2 = 117 KB/CU).
// NOTE __launch_bounds__(512,2): empirically the 2nd arg caps VGPR at
// ~256/N — (512,4) forced a 64-reg cap and spilled q[16] to scratch
// (r8: WRITE_SIZE 253 MB, 145 us). (512,2) -> ~120 VGPR, no spill; the
// 2-blocks/CU co-residency comes from the grid (512 blocks / 256 CUs).
// 4 phases: tiles of 2+2+2+1 rows. Group (ph&1) computes tile ph; the other
// group drains its 2-phase-old loads, ds_writes the next ring rows, stores
// its previously-computed tile, issues loads 2 phases ahead.
__launch_bounds__(512, 2)
__global__ void conv7_kernel(const int* __restrict__ x,
                             const int8_t* __restrict__ wt,
                             const float*  __restrict__ wscale,
                             const float*  __restrict__ ascale,
                             const float*  __restrict__ bias,
                             float*        __restrict__ out) {
    __shared__ int8_t xs[8 * ROWB];   // 58,368 B ring

    const int tid  = threadIdx.x;          // 0..511
    const int g    = tid >> 8;             // wave-group 0/1
    const int stid = tid & 255;            // id within group
    // XCD-chunked swizzle: 512 = 8 XCDs x 64 contiguous (b, hg) groups
    const int bt = ((blockIdx.x & 7) * 64) + (blockIdx.x >> 3);
    const int b  = bt >> 4;                // /16
    const int hb = (bt & 15) * 7;          // 7 output rows per block

    const int lane = tid & 63;
    const int wave = (tid >> 6) & 3;       // co-tile within group
    const int ln15 = lane & 15;
    const int quad = lane >> 4;

    // one-time: zero W-pad columns 0 and 113 of all 8 ring rows (256 jobs)
    if (tid < 256) {
        int pr   = tid >> 5;
        int side = (tid >> 4) & 1;
        int d    = tid & 15;
        *(uint32_t*)&xs[pr * ROWB + (side ? 113 : 0) * 64 + d * 4] = 0u;
    }

    // A fragments: wt[co][tap*64 + quad*16 .. +15]
    const v4i* wrow = (const v4i*)(wt + (size_t)(wave * 16 + ln15) * 576);
    v4i a[9];
    #pragma unroll
    for (int t = 0; t < 9; ++t) a[t] = wrow[t * 4 + quad];

    const float s = ascale[0] * wscale[0];
    float bv[4];
    #pragma unroll
    for (int reg = 0; reg < 4; ++reg) bv[reg] = bias[wave * 16 + quad * 4 + reg];

    // ---- group-local staging: load to regs / narrow+swizzle to LDS ----
    // 2-row: 896 jobs over 256 group-threads (4 int4 loads each, coalesced
    // 64B lines). 1-row: 448 jobs. OOB rows stay zero (H padding).
    v4i q[16];
    auto stage_load = [&](int hstart) {
        #pragma unroll
        for (int it = 0; it < 4; ++it) {
            #pragma unroll
            for (int p = 0; p < 4; ++p) q[it * 4 + p] = (v4i){0, 0, 0, 0};
            int job = stid + it * 256;
            if (job < 896) {
                int ci4  = job & 15;
                int cg   = (job >> 4) % 28;
                int row2 = job / 448;
                int hh   = hstart + row2;
                if (hh >= 0 && hh < HH) {
                    const v4i* gp = (const v4i*)
                        (x + ((size_t)(b * CIN + ci4 * 4) * HH + hh) * WW + cg * 4);
                    q[it * 4 + 0] = gp[0];
                    q[it * 4 + 1] = gp[3136];      // +1 ci plane
                    q[it * 4 + 2] = gp[2 * 3136];
                    q[it * 4 + 3] = gp[3 * 3136];
                }
            }
        }
    };
    auto stage_load1 = [&](int hh) {       // single row -> q[0..7]
        #pragma unroll
        for (int it = 0; it < 2; ++it) {
            #pragma unroll
            for (int p = 0; p < 4; ++p) q[it * 4 + p] = (v4i){0, 0, 0, 0};
            int job = stid + it * 256;
            if (job < 448 && hh >= 0 && hh < HH) {
                int ci4 = job & 15;
                int cg  = (job >> 4) % 28;
                const v4i* gp = (const v4i*)
                    (x + ((size_t)(b * CIN + ci4 * 4) * HH + hh) * WW + cg * 4);
                q[it * 4 + 0] = gp[0];
                q[it * 4 + 1] = gp[3136];
                q[it * 4 + 2] = gp[2 * 3136];
                q[it * 4 + 3] = gp[3 * 3136];
            }
        }
    };
    auto stage_write = [&](int pb) {       // 2 rows at ring pb, pb+1
        #pragma unroll
        for (int it = 0; it < 4; ++it) {
            int job = stid + it * 256;
            if (job < 896) {
                int ci4  = job & 15;
                int cg   = (job >> 4) % 28;
                int row2 = job / 448;
                int8_t* rowp = &xs[(pb + row2) * ROWB];
                #pragma unroll
                for (int j = 0; j < 4; ++j) {
                    uint32_t lo01 = __builtin_amdgcn_perm(
                        (uint32_t)q[it * 4 + 1][j], (uint32_t)q[it * 4 + 0][j], 0x0C0C0400u);
                    uint32_t lo23 = __builtin_amdgcn_perm(
                        (uint32_t)q[it * 4 + 3][j], (uint32_t)q[it * 4 + 2][j], 0x04000C0Cu);
                    int col = cg * 4 + 1 + j;   // +1: W-pad shift
                    int sd  = (((ci4 >> 2) ^ ((col >> 1) & 3)) << 2) | (ci4 & 3);
                    *(uint32_t*)&rowp[col * 64 + sd * 4] = lo01 | lo23;
                }
            }
        }
    };
    auto stage_write1 = [&](int pb) {      // 1 row at ring pb
        #pragma unroll
        for (int it = 0; it < 2; ++it) {
            int job = stid + it * 256;
            if (job < 448) {
                int ci4 = job & 15;
                int cg  = (job >> 4) % 28;
                int8_t* rowp = &xs[pb * ROWB];
                #pragma unroll
                for (int j = 0; j < 4; ++j) {
                    uint32_t lo01 = __builtin_amdgcn_perm(
                        (uint32_t)q[it * 4 + 1][j], (uint32_t)q[it * 4 + 0][j], 0x0C0C0400u);
                    uint32_t lo23 = __builtin_amdgcn_perm(
                        (uint32_t)q[it * 4 + 3][j], (uint32_t)q[it * 4 + 2][j], 0x04000C0Cu);
                    int col = cg * 4 + 1 + j;
                    int sd  = (((ci4 >> 2) ^ ((col >> 1) & 3)) << 2) | (ci4 & 3);
                    *(uint32_t*)&rowp[col * 64 + sd * 4] = lo01 | lo23;
                }
            }
        }
    };

    v4i acc[2][7];
    // 2-row tile at ring rows rbase..rbase+3 (never wraps for rbase 0/2/4);
    // each bfrag feeds acc[0] (kh=rho) and acc[1] (kh=rho-1):
    // 84 ds_read_b128 : 126 MFMA per wave, conflict-free swizzle.
    auto mfma_tile = [&](int rbase) {
        #pragma unroll
        for (int r = 0; r < 2; ++r)
            #pragma unroll
            for (int nt = 0; nt < 7; ++nt)
                acc[r][nt] = (v4i){0, 0, 0, 0};
        #pragma unroll
        for (int rho = 0; rho < 4; ++rho) {
            const int pr = rbase + rho;
            #pragma unroll
            for (int kw = 0; kw < 3; ++kw) {
                const int m   = ln15 + kw;
                const int swz = (quad ^ ((m >> 1) & 3)) << 4;
                const int8_t* bp = &xs[pr * ROWB + m * 64 + swz];
                #pragma unroll
                for (int nt = 0; nt < 7; ++nt) {
                    v4i bfrag = *(const v4i*)(bp + nt * 1024);
                    if (rho <= 2)
                        acc[0][nt] = __builtin_amdgcn_mfma_i32_16x16x64_i8(
                            a[rho * 3 + kw], bfrag, acc[0][nt], 0, 0, 0);
                    if (rho >= 1)
                        acc[1][nt] = __builtin_amdgcn_mfma_i32_16x16x64_i8(
                            a[(rho - 1) * 3 + kw], bfrag, acc[1][nt], 0, 0, 0);
                }
            }
        }
    };
    // single-row tile (out row hb+6): ring rows {6,7,0}, acc[0] only.
    auto mfma_last = [&]() {
        #pragma unroll
        for (int nt = 0; nt < 7; ++nt) acc[0][nt] = (v4i){0, 0, 0, 0};
        #pragma unroll
        for (int rho = 0; rho < 3; ++rho) {
            const int pr = (6 + rho) & 7;
            #pragma unroll
            for (int kw = 0; kw < 3; ++kw) {
                const int m   = ln15 + kw;
                const int swz = (quad ^ ((m >> 1) & 3)) << 4;
                const int8_t* bp = &xs[pr * ROWB + m * 64 + swz];
                #pragma unroll
                for (int nt = 0; nt < 7; ++nt) {
                    v4i bfrag = *(const v4i*)(bp + nt * 1024);
                    acc[0][nt] = __builtin_amdgcn_mfma_i32_16x16x64_i8(
                        a[rho * 3 + kw], bfrag, acc[0][nt], 0, 0, 0);
                }
            }
        }
    };
    auto store_tile = [&](int t) {         // 2 rows
        const int h0 = hb + 2 * t;
        #pragma unroll
        for (int r = 0; r < 2; ++r) {
            const int h = h0 + r;
            #pragma unroll
            for (int reg = 0; reg < 4; ++reg) {
                int co = wave * 16 + quad * 4 + reg;
                float* op = out + ((size_t)(b * COUT_ + co) * HH + h) * WW;
                #pragma unroll
                for (int nt = 0; nt < 7; ++nt)
                    op[nt * 16 + ln15] = (float)acc[r][nt][reg] * s + bv[reg];
            }
        }
    };
    auto store_last = [&]() {              // 1 row (hb+6), acc[0]
        const int h = hb + 6;
        #pragma unroll
        for (int reg = 0; reg < 4; ++reg) {
            int co = wave * 16 + quad * 4 + reg;
            float* op = out + ((size_t)(b * COUT_ + co) * HH + h) * WW;
            #pragma unroll
            for (int nt = 0; nt < 7; ++nt)
                op[nt * 16 + ln15] = (float)acc[0][nt][reg] * s + bv[reg];
        }
    };

    // ---- prologue ----
    // g0 stages ring 0,1 (in-rows hb-1,hb); g1 stages ring 2,3 (hb+1,hb+2)
    stage_load(hb - 1 + 2 * g);
    asm volatile("s_waitcnt vmcnt(0)" ::: "memory");
    stage_write(2 * g);
    // issue-ahead: g1 loads hb+3,hb+4 (writes ring 4,5 at ph0);
    //              g0 loads hb+5,hb+6 (writes ring 6,7 at ph1)
    stage_load(hb + 3 + 2 * (g ^ 1));
    asm volatile("s_waitcnt lgkmcnt(0)" ::: "memory");
    __builtin_amdgcn_s_barrier();
    __builtin_amdgcn_sched_barrier(0);

    // ---- ph0: g0 computes tile0 (rings 0-3); g1 writes rings 4,5 +
    //          issues the hb+7 load (ring 0 at ph2) ----
    if (g == 0) {
        __builtin_amdgcn_s_setprio(1);
        mfma_tile(0);
        __builtin_amdgcn_s_setprio(0);
    } else {
        asm volatile("s_waitcnt vmcnt(0)" ::: "memory");
        stage_write(4);
        stage_load1(hb + 7);
    }
    __builtin_amdgcn_sched_barrier(0);
    asm volatile("s_waitcnt lgkmcnt(0)" ::: "memory");
    __builtin_amdgcn_s_barrier();
    __builtin_amdgcn_sched_barrier(0);

    // ---- ph1: g1 computes tile1 (rings 2-5); g0 writes rings 6,7 and
    //          stores tile0 ----
    if (g == 1) {
        __builtin_amdgcn_s_setprio(1);
        mfma_tile(2);
        __builtin_amdgcn_s_setprio(0);
    } else {
        asm volatile("s_waitcnt vmcnt(0)" ::: "memory");
        stage_write(6);
        store_tile(0);
    }
    __builtin_amdgcn_sched_barrier(0);
    asm volatile("s_waitcnt lgkmcnt(0)" ::: "memory");
    __builtin_amdgcn_s_barrier();
    __builtin_amdgcn_sched_barrier(0);

    // ---- ph2: g0 computes tile2 (rings 4-7); g1 writes ring 0 (in-row
    //          hb+7; last read at ph0, barrier since) and stores tile1 ----
    if (g == 0) {
        __builtin_amdgcn_s_setprio(1);
        mfma_tile(4);
        __builtin_amdgcn_s_setprio(0);
    } else {
        asm volatile("s_waitcnt vmcnt(0)" ::: "memory");
        stage_write1(0);
        store_tile(1);
    }
    __builtin_amdgcn_sched_barrier(0);
    asm volatile("s_waitcnt lgkmcnt(0)" ::: "memory");
    __builtin_amdgcn_s_barrier();
    __builtin_amdgcn_sched_barrier(0);

    // ---- ph3: g1 computes the single-row tile3 (rings 6,7,0); g0 stores
    //          tile2; then g1 stores tile3 ----
    if (g == 1) {
        __builtin_amdgcn_s_setprio(1);
        mfma_last();
        __builtin_amdgcn_s_setprio(0);
        store_last();
    } else {
        store_tile(2);
    }
}

extern "C" void kernel_launch(void* const* d_in, const int* in_sizes, int n_in,
                              void* d_out, int out_size, void* d_ws, size_t ws_size,
                              hipStream_t stream) {
    const int*    xq     = (const int*)d_in[0];
    const int*    wq     = (const int*)d_in[1];
    const float*  wscale = (const float*)d_in[2];
    const float*  ascale = (const float*)d_in[3];
    const float*  bias   = (const float*)d_in[4];
    int8_t* wt  = (int8_t*)d_ws;          // 36,864 B scratch
    float*  out = (float*)d_out;

    wtrans_kernel<<<144, 256, 0, stream>>>(wq, wt);
    conv7_kernel<<<512, 512, 0, stream>>>(xq, wt, wscale, ascale, bias, out);
}